// Round 1
// baseline (596.824 us; speedup 1.0000x reference)
//
#include <hip/hip_runtime.h>

// ---------------------------------------------------------------------------
// Attention_73813307949177: out = ((softmax2(softmax1(qx kx^T + bias)*wei + bias)) kx) Wp^T + bp
//   qx = q Wq^T + bq ; kx = k Wk^T + bk ; bias = -1e16 where mask==0
// Outputs (concat): out [4096,1024] fp32, score2 [4096,4096] fp32
//
// Precision plan: score-feeding GEMMs use 2-way bf16 split (hi/lo, 3 MFMAs)
// -> ~17-bit mantissa, softmax inputs near-fp32-exact. Post-softmax GEMMs
// plain bf16 (error ~3e-5 on out, threshold ~1.6e-3).
// ---------------------------------------------------------------------------

typedef __bf16 bf16;
typedef __bf16 bf16x8 __attribute__((ext_vector_type(8)));
typedef __bf16 bf16x4 __attribute__((ext_vector_type(4)));
typedef float  f32x4  __attribute__((ext_vector_type(4)));

typedef __attribute__((address_space(1))) void as1_void;
typedef __attribute__((address_space(3))) void as3_void;

#define NQ  4096
#define NKK 4096
#define EMB 1024

#define BM 128
#define BN 128
#define BK 32

// async global->LDS, 16B per lane; LDS dest = wave-uniform base + lane*16
__device__ __forceinline__ void gld_lds16(const void* g, void* l) {
    __builtin_amdgcn_global_load_lds((as1_void*)g, (as3_void*)l, 16, 0, 0);
}

// ---------------------------------------------------------------------------
// fp32 -> bf16 hi/lo split (x ~= hi + lo, ~17-bit combined mantissa)
__global__ __launch_bounds__(256) void split_f32_bf16(
    const float* __restrict__ s, bf16* __restrict__ h, bf16* __restrict__ l, int n)
{
    const int i = (blockIdx.x * 256 + threadIdx.x) * 4;
    if (i >= n) return;
    f32x4 v = *(const f32x4*)(s + i);
    bf16x4 hv, lv;
#pragma unroll
    for (int c = 0; c < 4; c++) {
        float x = v[c];
        bf16 hh = (bf16)x;
        hv[c] = hh;
        lv[c] = (bf16)(x - (float)hh);
    }
    *(bf16x4*)(h + i) = hv;
    *(bf16x4*)(l + i) = lv;
}

__global__ __launch_bounds__(256) void f2b_kernel(
    const float* __restrict__ s, bf16* __restrict__ d, int n)
{
    const int i = (blockIdx.x * 256 + threadIdx.x) * 4;
    if (i >= n) return;
    f32x4 v = *(const f32x4*)(s + i);
    bf16x4 o;
#pragma unroll
    for (int c = 0; c < 4; c++) o[c] = (bf16)v[c];
    *(bf16x4*)(d + i) = o;
}

// bf16 [R,C] -> [C,R] transpose (32x32 LDS tile, +1 pad)
__global__ __launch_bounds__(256) void transpose_bf16(
    const bf16* __restrict__ src, bf16* __restrict__ dst, int R, int C)
{
    __shared__ bf16 tile[32][33];
    const int bx = blockIdx.x * 32;   // col base in src
    const int by = blockIdx.y * 32;   // row base in src
    const int tx = threadIdx.x & 31;
    const int ty = threadIdx.x >> 5;  // 0..7
#pragma unroll
    for (int r = 0; r < 4; r++)
        tile[ty + 8 * r][tx] = src[(size_t)(by + ty + 8 * r) * C + bx + tx];
    __syncthreads();
#pragma unroll
    for (int r = 0; r < 4; r++)
        dst[(size_t)(bx + ty + 8 * r) * R + by + tx] = tile[tx][ty + 8 * r];
}

// ---------------------------------------------------------------------------
// Plain bf16 gemm_bt: C[M,N] = A[M,K] * B[N,K]^T (+bias). m97 structure:
// 128x128 tile, BK=32, 4 waves 2x2 (64x64 each), 16x16x32 MFMA.
template<int OUT_BF16, int HAS_BIAS>
__global__ __launch_bounds__(256) void gemm_bt(
    const bf16* __restrict__ A, const bf16* __restrict__ B,
    const float* __restrict__ bias,
    float* __restrict__ Cf, bf16* __restrict__ Cb,
    int M, int N, int K)
{
    __shared__ bf16 sA[BM * BK];
    __shared__ bf16 sB[BN * BK];
    const int t    = threadIdx.x;
    const int wave = t >> 6;
    const int lane = t & 63;
    const int quad = lane >> 4;
    const int m16  = lane & 15;
    const int wm   = wave >> 1;
    const int wn   = wave & 1;
    const int bm   = blockIdx.y * BM;
    const int bn   = blockIdx.x * BN;
    const int srow = t >> 2;   // 0..63
    const int sseg = t & 3;    // 16B segment within 64B row

    const bf16* ga = A + (size_t)(bm + srow) * K + sseg * 8;
    const bf16* gb = B + (size_t)(bn + srow) * K + sseg * 8;
    char* lA = (char*)sA + wave * 1024;   // + lane*16 done by HW
    char* lB = (char*)sB + wave * 1024;

    f32x4 acc[4][4] = {};

    for (int k0 = 0; k0 < K; k0 += BK) {
        __syncthreads();
        gld_lds16(ga + k0,                    lA);
        gld_lds16(ga + (size_t)64 * K + k0,   lA + 4096);
        gld_lds16(gb + k0,                    lB);
        gld_lds16(gb + (size_t)64 * K + k0,   lB + 4096);
        __syncthreads();
        bf16x8 af[4], bfr[4];
#pragma unroll
        for (int i = 0; i < 4; i++)
            af[i] = *(const bf16x8*)&sA[(wm * 64 + i * 16 + m16) * BK + quad * 8];
#pragma unroll
        for (int j = 0; j < 4; j++)
            bfr[j] = *(const bf16x8*)&sB[(wn * 64 + j * 16 + m16) * BK + quad * 8];
#pragma unroll
        for (int i = 0; i < 4; i++)
#pragma unroll
            for (int j = 0; j < 4; j++)
                acc[i][j] = __builtin_amdgcn_mfma_f32_16x16x32_bf16(
                    af[i], bfr[j], acc[i][j], 0, 0, 0);
    }

    // C/D layout: col = lane&15, row = quad*4 + reg (verified m89/m91)
#pragma unroll
    for (int i = 0; i < 4; i++) {
        const int rg0 = bm + wm * 64 + i * 16 + quad * 4;
#pragma unroll
        for (int j = 0; j < 4; j++) {
            const int cg = bn + wn * 64 + j * 16 + m16;
            const float bv = HAS_BIAS ? bias[cg] : 0.0f;
#pragma unroll
            for (int r = 0; r < 4; r++) {
                const float v = acc[i][j][r] + bv;
                const size_t idx = (size_t)(rg0 + r) * N + cg;
                if (OUT_BF16) Cb[idx] = (bf16)v;
                else          Cf[idx] = v;
            }
        }
    }
}

// ---------------------------------------------------------------------------
// Split-precision gemm_bt: A,B given as bf16 hi/lo pairs of fp32 matrices.
// acc += Ah*Bh + Ah*Bl + Al*Bh  (drops Al*Bl, rel err ~2^-18).
// OUT_SPLIT=1: write bf16 hi/lo of result; OUT_SPLIT=0: write fp32.
template<int OUT_SPLIT, int HAS_BIAS>
__global__ __launch_bounds__(256) void gemm_bt_split(
    const bf16* __restrict__ Ah, const bf16* __restrict__ Al,
    const bf16* __restrict__ Bh, const bf16* __restrict__ Bl,
    const float* __restrict__ bias,
    float* __restrict__ Cf, bf16* __restrict__ Ch, bf16* __restrict__ Cl,
    int M, int N, int K)
{
    __shared__ bf16 sAh[BM * BK], sAl[BM * BK], sBh[BN * BK], sBl[BN * BK];
    const int t    = threadIdx.x;
    const int wave = t >> 6;
    const int lane = t & 63;
    const int quad = lane >> 4;
    const int m16  = lane & 15;
    const int wm   = wave >> 1;
    const int wn   = wave & 1;
    const int bm   = blockIdx.y * BM;
    const int bn   = blockIdx.x * BN;
    const int srow = t >> 2;
    const int sseg = t & 3;

    const size_t offA = (size_t)(bm + srow) * K + sseg * 8;
    const size_t offB = (size_t)(bn + srow) * K + sseg * 8;
    char* lAh = (char*)sAh + wave * 1024;
    char* lAl = (char*)sAl + wave * 1024;
    char* lBh = (char*)sBh + wave * 1024;
    char* lBl = (char*)sBl + wave * 1024;

    f32x4 acc[4][4] = {};

    for (int k0 = 0; k0 < K; k0 += BK) {
        __syncthreads();
        gld_lds16(Ah + offA + k0,                  lAh);
        gld_lds16(Ah + offA + (size_t)64 * K + k0, lAh + 4096);
        gld_lds16(Al + offA + k0,                  lAl);
        gld_lds16(Al + offA + (size_t)64 * K + k0, lAl + 4096);
        gld_lds16(Bh + offB + k0,                  lBh);
        gld_lds16(Bh + offB + (size_t)64 * K + k0, lBh + 4096);
        gld_lds16(Bl + offB + k0,                  lBl);
        gld_lds16(Bl + offB + (size_t)64 * K + k0, lBl + 4096);
        __syncthreads();
        bf16x8 ah[4], al[4], bh[4], bl[4];
#pragma unroll
        for (int i = 0; i < 4; i++) {
            const int ro = (wm * 64 + i * 16 + m16) * BK + quad * 8;
            ah[i] = *(const bf16x8*)&sAh[ro];
            al[i] = *(const bf16x8*)&sAl[ro];
        }
#pragma unroll
        for (int j = 0; j < 4; j++) {
            const int ro = (wn * 64 + j * 16 + m16) * BK + quad * 8;
            bh[j] = *(const bf16x8*)&sBh[ro];
            bl[j] = *(const bf16x8*)&sBl[ro];
        }
#pragma unroll
        for (int i = 0; i < 4; i++)
#pragma unroll
            for (int j = 0; j < 4; j++) {
                acc[i][j] = __builtin_amdgcn_mfma_f32_16x16x32_bf16(al[i], bh[j], acc[i][j], 0, 0, 0);
                acc[i][j] = __builtin_amdgcn_mfma_f32_16x16x32_bf16(ah[i], bl[j], acc[i][j], 0, 0, 0);
                acc[i][j] = __builtin_amdgcn_mfma_f32_16x16x32_bf16(ah[i], bh[j], acc[i][j], 0, 0, 0);
            }
    }

#pragma unroll
    for (int i = 0; i < 4; i++) {
        const int rg0 = bm + wm * 64 + i * 16 + quad * 4;
#pragma unroll
        for (int j = 0; j < 4; j++) {
            const int cg = bn + wn * 64 + j * 16 + m16;
            const float bv = HAS_BIAS ? bias[cg] : 0.0f;
#pragma unroll
            for (int r = 0; r < 4; r++) {
                const float v = acc[i][j][r] + bv;
                const size_t idx = (size_t)(rg0 + r) * N + cg;
                if (OUT_SPLIT) {
                    const bf16 hh = (bf16)v;
                    Ch[idx] = hh;
                    Cl[idx] = (bf16)(v - (float)hh);
                } else {
                    Cf[idx] = v;
                }
            }
        }
    }
}

// ---------------------------------------------------------------------------
// Fused double softmax over one row per block (row = 4096 = 256 thr x 16).
// In-place fp32 result + bf16 copy for the ctx GEMM. mask==0 -> p=0 exactly
// (matches exp(-1e16 - m) == 0 in fp32).
__device__ __forceinline__ float wred_max(float v) {
#pragma unroll
    for (int off = 32; off > 0; off >>= 1) v = fmaxf(v, __shfl_xor(v, off));
    return v;
}
__device__ __forceinline__ float wred_sum(float v) {
#pragma unroll
    for (int off = 32; off > 0; off >>= 1) v += __shfl_xor(v, off);
    return v;
}

__global__ __launch_bounds__(256) void softmax2_kernel(
    float* __restrict__ score, const int* __restrict__ mask,
    const float* __restrict__ wei, bf16* __restrict__ scoreb)
{
    __shared__ float sred[4];
    const int row = blockIdx.x;
    const int t   = threadIdx.x;
    const size_t base = (size_t)row * NKK;
    const int wv = t >> 6, ln = t & 63;

    float l[16], w[16];
    unsigned mb = 0;
#pragma unroll
    for (int s = 0; s < 16; s++) {
        const int j = t + (s << 8);
        l[s] = score[base + j];
        w[s] = wei[base + j];
        if (mask[base + j] != 0) mb |= 1u << s;
    }

    // pass 1
    float mx = -__builtin_inff();
#pragma unroll
    for (int s = 0; s < 16; s++) if (mb & (1u << s)) mx = fmaxf(mx, l[s]);
    mx = wred_max(mx);
    if (ln == 0) sred[wv] = mx;
    __syncthreads();
    mx = fmaxf(fmaxf(sred[0], sred[1]), fmaxf(sred[2], sred[3]));
    __syncthreads();
    float sum = 0.f;
#pragma unroll
    for (int s = 0; s < 16; s++) {
        const float e = (mb & (1u << s)) ? __expf(l[s] - mx) : 0.f;
        l[s] = e; sum += e;
    }
    sum = wred_sum(sum);
    if (ln == 0) sred[wv] = sum;
    __syncthreads();
    sum = sred[0] + sred[1] + sred[2] + sred[3];
    __syncthreads();
    const float inv1 = 1.0f / sum;

    // logits2 = p1 * wei (masked lanes already 0; mask reapplied below)
#pragma unroll
    for (int s = 0; s < 16; s++) l[s] = l[s] * inv1 * w[s];

    // pass 2
    float mx2 = -__builtin_inff();
#pragma unroll
    for (int s = 0; s < 16; s++) if (mb & (1u << s)) mx2 = fmaxf(mx2, l[s]);
    mx2 = wred_max(mx2);
    if (ln == 0) sred[wv] = mx2;
    __syncthreads();
    mx2 = fmaxf(fmaxf(sred[0], sred[1]), fmaxf(sred[2], sred[3]));
    __syncthreads();
    float sum2 = 0.f;
#pragma unroll
    for (int s = 0; s < 16; s++) {
        const float e = (mb & (1u << s)) ? __expf(l[s] - mx2) : 0.f;
        l[s] = e; sum2 += e;
    }
    sum2 = wred_sum(sum2);
    if (ln == 0) sred[wv] = sum2;
    __syncthreads();
    sum2 = sred[0] + sred[1] + sred[2] + sred[3];
    const float inv2 = 1.0f / sum2;

#pragma unroll
    for (int s = 0; s < 16; s++) {
        const int j = t + (s << 8);
        const float p = l[s] * inv2;
        score[base + j]  = p;
        scoreb[base + j] = (bf16)p;
    }
}

// ---------------------------------------------------------------------------
extern "C" void kernel_launch(void* const* d_in, const int* in_sizes, int n_in,
                              void* d_out, int out_size, void* d_ws, size_t ws_size,
                              hipStream_t stream)
{
    (void)in_sizes; (void)n_in; (void)out_size;
    const float* q    = (const float*)d_in[0];
    const float* k    = (const float*)d_in[1];
    const int*   mask = (const int*)  d_in[2];
    const float* wei  = (const float*)d_in[3];
    const float* Wq   = (const float*)d_in[4];
    const float* bq   = (const float*)d_in[5];
    const float* Wk   = (const float*)d_in[6];
    const float* bk   = (const float*)d_in[7];
    const float* Wp   = (const float*)d_in[8];
    const float* bp   = (const float*)d_in[9];

    float* out   = (float*)d_out;                       // [4096,1024]
    float* score = (float*)d_out + (size_t)NQ * EMB;    // [4096,4096] logits->p2 in place

    char* ws = (char*)d_ws;
    size_t off = 0;
    auto alloc = [&](size_t bytes) -> char* {
        char* p = ws + off; off += (bytes + 255) & ~(size_t)255; return p;
    };
    const size_t n_qk = (size_t)NQ * EMB;     // 4.19M elems
    const size_t n_w  = (size_t)EMB * EMB;    // 1.05M elems
    const size_t n_sc = (size_t)NQ * NKK;     // 16.8M elems

    bf16* qh   = (bf16*)alloc(n_qk * 2);
    bf16* ql   = (bf16*)alloc(n_qk * 2);
    bf16* kh   = (bf16*)alloc(n_qk * 2);
    bf16* kl   = (bf16*)alloc(n_qk * 2);
    bf16* qxh  = (bf16*)alloc(n_qk * 2);
    bf16* qxl  = (bf16*)alloc(n_qk * 2);
    bf16* kxh  = (bf16*)alloc(n_qk * 2);
    bf16* kxl  = (bf16*)alloc(n_qk * 2);
    bf16* Wqh  = (bf16*)alloc(n_w * 2);
    bf16* Wql  = (bf16*)alloc(n_w * 2);
    bf16* Wkh  = (bf16*)alloc(n_w * 2);
    bf16* Wkl  = (bf16*)alloc(n_w * 2);
    bf16* Wpb  = (bf16*)alloc(n_w * 2);
    bf16* kxTb = (bf16*)alloc(n_qk * 2);      // [EMB, NKK]
    bf16* ctxb = (bf16*)alloc(n_qk * 2);      // [NQ, EMB]
    bf16* scoreb = (bf16*)alloc(n_sc * 2);    // [NQ, NKK]
    if (off > ws_size) return;  // workspace too small -> fail loudly via mismatch

    // 1) input splits / converts
    split_f32_bf16<<<dim3(n_qk / 1024), 256, 0, stream>>>(q,  qh,  ql,  (int)n_qk);
    split_f32_bf16<<<dim3(n_qk / 1024), 256, 0, stream>>>(k,  kh,  kl,  (int)n_qk);
    split_f32_bf16<<<dim3(n_w  / 1024), 256, 0, stream>>>(Wq, Wqh, Wql, (int)n_w);
    split_f32_bf16<<<dim3(n_w  / 1024), 256, 0, stream>>>(Wk, Wkh, Wkl, (int)n_w);
    f2b_kernel    <<<dim3(n_w  / 1024), 256, 0, stream>>>(Wp, Wpb, (int)n_w);

    // 2) projections (split precision, split bf16 outputs)
    gemm_bt_split<1, 1><<<dim3(EMB / BN, NQ / BM), 256, 0, stream>>>(
        qh, ql, Wqh, Wql, bq, nullptr, qxh, qxl, NQ, EMB, EMB);
    gemm_bt_split<1, 1><<<dim3(EMB / BN, NKK / BM), 256, 0, stream>>>(
        kh, kl, Wkh, Wkl, bk, nullptr, kxh, kxl, NKK, EMB, EMB);

    // 3) kx^T (bf16 hi only; feeds post-softmax plain-bf16 ctx GEMM)
    transpose_bf16<<<dim3(EMB / 32, NKK / 32), 256, 0, stream>>>(kxh, kxTb, NKK, EMB);

    // 4) score logits = qx kx^T (split precision, fp32 out, in d_out score region)
    gemm_bt_split<0, 0><<<dim3(NKK / BN, NQ / BM), 256, 0, stream>>>(
        qxh, qxl, kxh, kxl, nullptr, score, nullptr, nullptr, NQ, NKK, EMB);

    // 5) fused double softmax (writes fp32 p2 in place + bf16 copy)
    softmax2_kernel<<<dim3(NQ), 256, 0, stream>>>(score, mask, wei, scoreb);

    // 6) ctx = p2 @ kx   (plain bf16)
    gemm_bt<1, 0><<<dim3(EMB / BN, NQ / BM), 256, 0, stream>>>(
        scoreb, kxTb, nullptr, nullptr, ctxb, NQ, EMB, NKK);

    // 7) out = ctx @ Wp^T + bp  (plain bf16, fp32 out)
    gemm_bt<0, 1><<<dim3(EMB / BN, NQ / BM), 256, 0, stream>>>(
        ctxb, Wpb, bp, out, nullptr, NQ, EMB, EMB);
}

// Round 2
// 553.714 us; speedup vs baseline: 1.0779x; 1.0779x over previous
//
#include <hip/hip_runtime.h>

// ---------------------------------------------------------------------------
// Attention_73813307949177
//   kx = k Wk^T + bk ; qx = q Wq^T + bq
//   score = softmax2(softmax1(qx kx^T + bias)*wei + bias)
//   out = (score kx) Wp^T + bp
// Outputs (concat): out [4096,1024] fp32, score [4096,4096] fp32
//
// R1 -> R2: every N=1024 GEMM had grid=256 (1 block/CU, 11% occupancy).
// Batch qx/kx proj (z) + split-K=2; split-K=4 on ctx and out GEMMs; fp32
// partials in a shared 67MB ws region + vectorized reduce kernels.
// Fallback to non-split path if ws_size too small (constant branch, graph-safe).
// ---------------------------------------------------------------------------

typedef __bf16 bf16;
typedef __bf16 bf16x8 __attribute__((ext_vector_type(8)));
typedef __bf16 bf16x4 __attribute__((ext_vector_type(4)));
typedef float  f32x4  __attribute__((ext_vector_type(4)));

typedef __attribute__((address_space(1))) void as1_void;
typedef __attribute__((address_space(3))) void as3_void;

#define NQ  4096
#define NKK 4096
#define EMB 1024

#define BM 128
#define BN 128
#define BK 32

__device__ __forceinline__ void gld_lds16(const void* g, void* l) {
    __builtin_amdgcn_global_load_lds((as1_void*)g, (as3_void*)l, 16, 0, 0);
}

// ---------------------------------------------------------------------------
__global__ __launch_bounds__(256) void split_f32_bf16(
    const float* __restrict__ s, bf16* __restrict__ h, bf16* __restrict__ l, int n)
{
    const int i = (blockIdx.x * 256 + threadIdx.x) * 4;
    if (i >= n) return;
    f32x4 v = *(const f32x4*)(s + i);
    bf16x4 hv, lv;
#pragma unroll
    for (int c = 0; c < 4; c++) {
        float x = v[c];
        bf16 hh = (bf16)x;
        hv[c] = hh;
        lv[c] = (bf16)(x - (float)hh);
    }
    *(bf16x4*)(h + i) = hv;
    *(bf16x4*)(l + i) = lv;
}

__global__ __launch_bounds__(256) void f2b_kernel(
    const float* __restrict__ s, bf16* __restrict__ d, int n)
{
    const int i = (blockIdx.x * 256 + threadIdx.x) * 4;
    if (i >= n) return;
    f32x4 v = *(const f32x4*)(s + i);
    bf16x4 o;
#pragma unroll
    for (int c = 0; c < 4; c++) o[c] = (bf16)v[c];
    *(bf16x4*)(d + i) = o;
}

__global__ __launch_bounds__(256) void transpose_bf16(
    const bf16* __restrict__ src, bf16* __restrict__ dst, int R, int C)
{
    __shared__ bf16 tile[32][33];
    const int bx = blockIdx.x * 32;
    const int by = blockIdx.y * 32;
    const int tx = threadIdx.x & 31;
    const int ty = threadIdx.x >> 5;
#pragma unroll
    for (int r = 0; r < 4; r++)
        tile[ty + 8 * r][tx] = src[(size_t)(by + ty + 8 * r) * C + bx + tx];
    __syncthreads();
#pragma unroll
    for (int r = 0; r < 4; r++)
        dst[(size_t)(bx + ty + 8 * r) * R + by + tx] = tile[tx][ty + 8 * r];
}

// ---------------------------------------------------------------------------
// Generic reduce over NS partial slices of n fp32 elems each.
// MODE 0: sum -> bf16(oh). MODE 1: sum+bias -> f32(of). MODE 2: sum+bias -> hi/lo bf16.
template<int NS, int MODE>
__global__ __launch_bounds__(256) void reduce_k(
    const float* __restrict__ P, const float* __restrict__ bias,
    float* __restrict__ of, bf16* __restrict__ oh, bf16* __restrict__ ol,
    int n, int Nld)
{
    const int i = (blockIdx.x * 256 + threadIdx.x) * 4;
    if (i >= n) return;
    f32x4 v = *(const f32x4*)(P + i);
#pragma unroll
    for (int s = 1; s < NS; s++)
        v += *(const f32x4*)(P + (size_t)s * n + i);
    if (MODE >= 1)
        v += *(const f32x4*)(bias + (i & (Nld - 1)));
    if (MODE == 0) {
        bf16x4 o;
#pragma unroll
        for (int c = 0; c < 4; c++) o[c] = (bf16)v[c];
        *(bf16x4*)(oh + i) = o;
    } else if (MODE == 1) {
        *(f32x4*)(of + i) = v;
    } else {
        bf16x4 h, l;
#pragma unroll
        for (int c = 0; c < 4; c++) {
            bf16 hh = (bf16)v[c];
            h[c] = hh;
            l[c] = (bf16)(v[c] - (float)hh);
        }
        *(bf16x4*)(oh + i) = h;
        *(bf16x4*)(ol + i) = l;
    }
}

// ---------------------------------------------------------------------------
// Plain bf16 gemm_bt: C[M,N] = A[M,K] * B[N,K]^T. m97 structure, 128x128 tile.
// NSPLIT>0: blockIdx.z = kz, writes fp32 partial slice kz (no bias).
template<int NSPLIT, int HAS_BIAS, int OUT_BF16>
__global__ __launch_bounds__(256) void gemm_bt(
    const bf16* __restrict__ A, const bf16* __restrict__ B,
    const float* __restrict__ bias,
    float* __restrict__ Cf, bf16* __restrict__ Cb,
    int M, int N, int Ksub, int lda, int ldb)
{
    __shared__ bf16 sA[BM * BK];
    __shared__ bf16 sB[BN * BK];
    const int t    = threadIdx.x;
    const int wave = t >> 6;
    const int lane = t & 63;
    const int quad = lane >> 4;
    const int m16  = lane & 15;
    const int wm   = wave >> 1;
    const int wn   = wave & 1;
    const int bm   = blockIdx.y * BM;
    const int bn   = blockIdx.x * BN;
    const int srow = t >> 2;
    const int sseg = t & 3;
    const int kz   = (NSPLIT > 0) ? (int)blockIdx.z : 0;

    A += (size_t)kz * Ksub;
    B += (size_t)kz * Ksub;
    if (NSPLIT > 0) Cf += (size_t)kz * M * N;

    const bf16* ga = A + (size_t)(bm + srow) * lda + sseg * 8;
    const bf16* gb = B + (size_t)(bn + srow) * ldb + sseg * 8;
    char* lA = (char*)sA + wave * 1024;
    char* lB = (char*)sB + wave * 1024;

    f32x4 acc[4][4] = {};

    for (int k0 = 0; k0 < Ksub; k0 += BK) {
        __syncthreads();
        gld_lds16(ga + k0,                      lA);
        gld_lds16(ga + (size_t)64 * lda + k0,   lA + 4096);
        gld_lds16(gb + k0,                      lB);
        gld_lds16(gb + (size_t)64 * ldb + k0,   lB + 4096);
        __syncthreads();
        bf16x8 af[4], bfr[4];
#pragma unroll
        for (int i = 0; i < 4; i++)
            af[i] = *(const bf16x8*)&sA[(wm * 64 + i * 16 + m16) * BK + quad * 8];
#pragma unroll
        for (int j = 0; j < 4; j++)
            bfr[j] = *(const bf16x8*)&sB[(wn * 64 + j * 16 + m16) * BK + quad * 8];
#pragma unroll
        for (int i = 0; i < 4; i++)
#pragma unroll
            for (int j = 0; j < 4; j++)
                acc[i][j] = __builtin_amdgcn_mfma_f32_16x16x32_bf16(
                    af[i], bfr[j], acc[i][j], 0, 0, 0);
    }

#pragma unroll
    for (int i = 0; i < 4; i++) {
        const int rg0 = bm + wm * 64 + i * 16 + quad * 4;
#pragma unroll
        for (int j = 0; j < 4; j++) {
            const int cg = bn + wn * 64 + j * 16 + m16;
            const float bv = HAS_BIAS ? bias[cg] : 0.0f;
#pragma unroll
            for (int r = 0; r < 4; r++) {
                const float v = acc[i][j][r] + bv;
                const size_t idx = (size_t)(rg0 + r) * N + cg;
                if (NSPLIT > 0)    Cf[idx] = v;
                else if (OUT_BF16) Cb[idx] = (bf16)v;
                else               Cf[idx] = v;
            }
        }
    }
}

// ---------------------------------------------------------------------------
// Split-precision gemm_bt (3 MFMAs: AhBh + AhBl + AlBh).
// BATCH: blockIdx.z selects {A0/B0} vs {A1/B1} operand sets.
// NSPLIT>0: split-K, fp32 partials (slice mt*NSPLIT+kz), no bias/hilo.
// NSPLIT==0: HILO? write bf16 hi/lo (+bias) : write fp32 (+bias if HAS_BIAS).
template<int BATCH, int NSPLIT, int HAS_BIAS, int HILO>
__global__ __launch_bounds__(256) void gemm_bt_split(
    const bf16* __restrict__ Ah0, const bf16* __restrict__ Al0,
    const bf16* __restrict__ Bh0, const bf16* __restrict__ Bl0,
    const float* __restrict__ bias0, bf16* __restrict__ Ch0, bf16* __restrict__ Cl0,
    const bf16* __restrict__ Ah1, const bf16* __restrict__ Al1,
    const bf16* __restrict__ Bh1, const bf16* __restrict__ Bl1,
    const float* __restrict__ bias1, bf16* __restrict__ Ch1, bf16* __restrict__ Cl1,
    float* __restrict__ P, float* __restrict__ Cf,
    int M, int N, int Ksub, int lda, int ldb)
{
    __shared__ bf16 sAh[BM * BK], sAl[BM * BK], sBh[BN * BK], sBl[BN * BK];
    const int t    = threadIdx.x;
    const int wave = t >> 6;
    const int lane = t & 63;
    const int quad = lane >> 4;
    const int m16  = lane & 15;
    const int wm   = wave >> 1;
    const int wn   = wave & 1;
    const int bm   = blockIdx.y * BM;
    const int bn   = blockIdx.x * BN;
    const int srow = t >> 2;
    const int sseg = t & 3;

    const int zs = (NSPLIT > 0) ? NSPLIT : 1;
    const int mt = BATCH ? ((int)blockIdx.z / zs) : 0;
    const int kz = (NSPLIT > 0) ? ((int)blockIdx.z % zs) : 0;

    const bf16* Ah = (BATCH && mt) ? Ah1 : Ah0;
    const bf16* Al = (BATCH && mt) ? Al1 : Al0;
    const bf16* Bh = (BATCH && mt) ? Bh1 : Bh0;
    const bf16* Bl = (BATCH && mt) ? Bl1 : Bl0;
    const float* bias = (BATCH && mt) ? bias1 : bias0;
    bf16* Ch = (BATCH && mt) ? Ch1 : Ch0;
    bf16* Cl = (BATCH && mt) ? Cl1 : Cl0;
    if (NSPLIT > 0) P += (size_t)(mt * zs + kz) * M * N;

    const size_t offA = (size_t)(bm + srow) * lda + sseg * 8 + (size_t)kz * Ksub;
    const size_t offB = (size_t)(bn + srow) * ldb + sseg * 8 + (size_t)kz * Ksub;
    char* lAh = (char*)sAh + wave * 1024;
    char* lAl = (char*)sAl + wave * 1024;
    char* lBh = (char*)sBh + wave * 1024;
    char* lBl = (char*)sBl + wave * 1024;

    f32x4 acc[4][4] = {};

    for (int k0 = 0; k0 < Ksub; k0 += BK) {
        __syncthreads();
        gld_lds16(Ah + offA + k0,                    lAh);
        gld_lds16(Ah + offA + (size_t)64 * lda + k0, lAh + 4096);
        gld_lds16(Al + offA + k0,                    lAl);
        gld_lds16(Al + offA + (size_t)64 * lda + k0, lAl + 4096);
        gld_lds16(Bh + offB + k0,                    lBh);
        gld_lds16(Bh + offB + (size_t)64 * ldb + k0, lBh + 4096);
        gld_lds16(Bl + offB + k0,                    lBl);
        gld_lds16(Bl + offB + (size_t)64 * ldb + k0, lBl + 4096);
        __syncthreads();
        bf16x8 ah[4], al[4], bh[4], bl[4];
#pragma unroll
        for (int i = 0; i < 4; i++) {
            const int ro = (wm * 64 + i * 16 + m16) * BK + quad * 8;
            ah[i] = *(const bf16x8*)&sAh[ro];
            al[i] = *(const bf16x8*)&sAl[ro];
        }
#pragma unroll
        for (int j = 0; j < 4; j++) {
            const int ro = (wn * 64 + j * 16 + m16) * BK + quad * 8;
            bh[j] = *(const bf16x8*)&sBh[ro];
            bl[j] = *(const bf16x8*)&sBl[ro];
        }
#pragma unroll
        for (int i = 0; i < 4; i++)
#pragma unroll
            for (int j = 0; j < 4; j++) {
                acc[i][j] = __builtin_amdgcn_mfma_f32_16x16x32_bf16(al[i], bh[j], acc[i][j], 0, 0, 0);
                acc[i][j] = __builtin_amdgcn_mfma_f32_16x16x32_bf16(ah[i], bl[j], acc[i][j], 0, 0, 0);
                acc[i][j] = __builtin_amdgcn_mfma_f32_16x16x32_bf16(ah[i], bh[j], acc[i][j], 0, 0, 0);
            }
    }

#pragma unroll
    for (int i = 0; i < 4; i++) {
        const int rg0 = bm + wm * 64 + i * 16 + quad * 4;
#pragma unroll
        for (int j = 0; j < 4; j++) {
            const int cg = bn + wn * 64 + j * 16 + m16;
            const float bv = (NSPLIT == 0 && HAS_BIAS) ? bias[cg] : 0.0f;
#pragma unroll
            for (int r = 0; r < 4; r++) {
                const float v = acc[i][j][r] + bv;
                const size_t idx = (size_t)(rg0 + r) * N + cg;
                if (NSPLIT > 0) {
                    P[idx] = v;
                } else if (HILO) {
                    const bf16 hh = (bf16)v;
                    Ch[idx] = hh;
                    Cl[idx] = (bf16)(v - (float)hh);
                } else {
                    Cf[idx] = v;
                }
            }
        }
    }
}

// ---------------------------------------------------------------------------
__device__ __forceinline__ float wred_max(float v) {
#pragma unroll
    for (int off = 32; off > 0; off >>= 1) v = fmaxf(v, __shfl_xor(v, off));
    return v;
}
__device__ __forceinline__ float wred_sum(float v) {
#pragma unroll
    for (int off = 32; off > 0; off >>= 1) v += __shfl_xor(v, off);
    return v;
}

__global__ __launch_bounds__(256) void softmax2_kernel(
    float* __restrict__ score, const int* __restrict__ mask,
    const float* __restrict__ wei, bf16* __restrict__ scoreb)
{
    __shared__ float sred[4];
    const int row = blockIdx.x;
    const int t   = threadIdx.x;
    const size_t base = (size_t)row * NKK;
    const int wv = t >> 6, ln = t & 63;

    float l[16], w[16];
    unsigned mb = 0;
#pragma unroll
    for (int s = 0; s < 16; s++) {
        const int j = t + (s << 8);
        l[s] = score[base + j];
        w[s] = wei[base + j];
        if (mask[base + j] != 0) mb |= 1u << s;
    }

    float mx = -__builtin_inff();
#pragma unroll
    for (int s = 0; s < 16; s++) if (mb & (1u << s)) mx = fmaxf(mx, l[s]);
    mx = wred_max(mx);
    if (ln == 0) sred[wv] = mx;
    __syncthreads();
    mx = fmaxf(fmaxf(sred[0], sred[1]), fmaxf(sred[2], sred[3]));
    __syncthreads();
    float sum = 0.f;
#pragma unroll
    for (int s = 0; s < 16; s++) {
        const float e = (mb & (1u << s)) ? __expf(l[s] - mx) : 0.f;
        l[s] = e; sum += e;
    }
    sum = wred_sum(sum);
    if (ln == 0) sred[wv] = sum;
    __syncthreads();
    sum = sred[0] + sred[1] + sred[2] + sred[3];
    __syncthreads();
    const float inv1 = 1.0f / sum;

#pragma unroll
    for (int s = 0; s < 16; s++) l[s] = l[s] * inv1 * w[s];

    float mx2 = -__builtin_inff();
#pragma unroll
    for (int s = 0; s < 16; s++) if (mb & (1u << s)) mx2 = fmaxf(mx2, l[s]);
    mx2 = wred_max(mx2);
    if (ln == 0) sred[wv] = mx2;
    __syncthreads();
    mx2 = fmaxf(fmaxf(sred[0], sred[1]), fmaxf(sred[2], sred[3]));
    __syncthreads();
    float sum2 = 0.f;
#pragma unroll
    for (int s = 0; s < 16; s++) {
        const float e = (mb & (1u << s)) ? __expf(l[s] - mx2) : 0.f;
        l[s] = e; sum2 += e;
    }
    sum2 = wred_sum(sum2);
    if (ln == 0) sred[wv] = sum2;
    __syncthreads();
    sum2 = sred[0] + sred[1] + sred[2] + sred[3];
    const float inv2 = 1.0f / sum2;

#pragma unroll
    for (int s = 0; s < 16; s++) {
        const int j = t + (s << 8);
        const float p = l[s] * inv2;
        score[base + j]  = p;
        scoreb[base + j] = (bf16)p;
    }
}

// ---------------------------------------------------------------------------
extern "C" void kernel_launch(void* const* d_in, const int* in_sizes, int n_in,
                              void* d_out, int out_size, void* d_ws, size_t ws_size,
                              hipStream_t stream)
{
    (void)in_sizes; (void)n_in; (void)out_size;
    const float* q    = (const float*)d_in[0];
    const float* k    = (const float*)d_in[1];
    const int*   mask = (const int*)  d_in[2];
    const float* wei  = (const float*)d_in[3];
    const float* Wq   = (const float*)d_in[4];
    const float* bq   = (const float*)d_in[5];
    const float* Wk   = (const float*)d_in[6];
    const float* bk   = (const float*)d_in[7];
    const float* Wp   = (const float*)d_in[8];
    const float* bp   = (const float*)d_in[9];

    float* out   = (float*)d_out;
    float* score = (float*)d_out + (size_t)NQ * EMB;

    char* ws = (char*)d_ws;
    size_t off = 0;
    auto alloc = [&](size_t bytes) -> char* {
        char* p = ws + off; off += (bytes + 255) & ~(size_t)255; return p;
    };
    const size_t n_qk = (size_t)NQ * EMB;
    const size_t n_w  = (size_t)EMB * EMB;
    const size_t n_sc = (size_t)NQ * NKK;

    bf16* qh   = (bf16*)alloc(n_qk * 2);
    bf16* ql   = (bf16*)alloc(n_qk * 2);
    bf16* kh   = (bf16*)alloc(n_qk * 2);
    bf16* kl   = (bf16*)alloc(n_qk * 2);
    bf16* qxh  = (bf16*)alloc(n_qk * 2);
    bf16* qxl  = (bf16*)alloc(n_qk * 2);
    bf16* kxh  = (bf16*)alloc(n_qk * 2);
    bf16* kxl  = (bf16*)alloc(n_qk * 2);
    bf16* Wqh  = (bf16*)alloc(n_w * 2);
    bf16* Wql  = (bf16*)alloc(n_w * 2);
    bf16* Wkh  = (bf16*)alloc(n_w * 2);
    bf16* Wkl  = (bf16*)alloc(n_w * 2);
    bf16* Wpb  = (bf16*)alloc(n_w * 2);
    bf16* kxTb = (bf16*)alloc(n_qk * 2);
    bf16* ctxb = (bf16*)alloc(n_qk * 2);
    bf16* scoreb = (bf16*)alloc(n_sc * 2);
    const size_t base_off = off;
    float* P = (float*)alloc(4 * n_qk * 4);   // 67 MB shared partials region
    const bool ws_ok = (off <= ws_size);
    if (base_off > ws_size) return;           // even round-1 layout doesn't fit

    const int MN = (int)n_qk;                 // 4.19M

    // 1) input splits / converts
    split_f32_bf16<<<dim3(n_qk / 1024), 256, 0, stream>>>(q,  qh,  ql,  (int)n_qk);
    split_f32_bf16<<<dim3(n_qk / 1024), 256, 0, stream>>>(k,  kh,  kl,  (int)n_qk);
    split_f32_bf16<<<dim3(n_w  / 1024), 256, 0, stream>>>(Wq, Wqh, Wql, (int)n_w);
    split_f32_bf16<<<dim3(n_w  / 1024), 256, 0, stream>>>(Wk, Wkh, Wkl, (int)n_w);
    f2b_kernel    <<<dim3(n_w  / 1024), 256, 0, stream>>>(Wp, Wpb, (int)n_w);

    // 2) projections: batched (z) + split-K=2 -> 1024 blocks
    if (ws_ok) {
        gemm_bt_split<1, 2, 0, 0><<<dim3(EMB / BN, NQ / BM, 4), 256, 0, stream>>>(
            qh, ql, Wqh, Wql, nullptr, nullptr, nullptr,
            kh, kl, Wkh, Wkl, nullptr, nullptr, nullptr,
            P, nullptr, NQ, EMB, EMB / 2, EMB, EMB);
        reduce_k<2, 2><<<dim3(MN / 1024), 256, 0, stream>>>(
            P,                 bq, nullptr, qxh, qxl, MN, EMB);
        reduce_k<2, 2><<<dim3(MN / 1024), 256, 0, stream>>>(
            P + 2 * n_qk,      bk, nullptr, kxh, kxl, MN, EMB);
    } else {
        gemm_bt_split<1, 0, 1, 1><<<dim3(EMB / BN, NQ / BM, 2), 256, 0, stream>>>(
            qh, ql, Wqh, Wql, bq, qxh, qxl,
            kh, kl, Wkh, Wkl, bk, kxh, kxl,
            nullptr, nullptr, NQ, EMB, EMB, EMB, EMB);
    }

    // 3) kx^T for the ctx GEMM's B operand
    transpose_bf16<<<dim3(EMB / 32, NKK / 32), 256, 0, stream>>>(kxh, kxTb, NKK, EMB);

    // 4) score logits = qx kx^T (split precision, fp32 into d_out score region)
    gemm_bt_split<0, 0, 0, 0><<<dim3(NKK / BN, NQ / BM), 256, 0, stream>>>(
        qxh, qxl, kxh, kxl, nullptr, nullptr, nullptr,
        nullptr, nullptr, nullptr, nullptr, nullptr, nullptr, nullptr,
        nullptr, score, NQ, NKK, EMB, EMB, EMB);

    // 5) fused double softmax (fp32 in place + bf16 copy)
    softmax2_kernel<<<dim3(NQ), 256, 0, stream>>>(score, mask, wei, scoreb);

    // 6) ctx = p2 @ kx  (split-K=4 -> 1024 blocks)
    if (ws_ok) {
        gemm_bt<4, 0, 0><<<dim3(EMB / BN, NQ / BM, 4), 256, 0, stream>>>(
            scoreb, kxTb, nullptr, P, nullptr, NQ, EMB, NKK / 4, NKK, NKK);
        reduce_k<4, 0><<<dim3(MN / 1024), 256, 0, stream>>>(
            P, nullptr, nullptr, ctxb, nullptr, MN, EMB);
    } else {
        gemm_bt<0, 0, 1><<<dim3(EMB / BN, NQ / BM), 256, 0, stream>>>(
            scoreb, kxTb, nullptr, nullptr, ctxb, NQ, EMB, NKK, NKK, NKK);
    }

    // 7) out = ctx @ Wp^T + bp  (split-K=4 -> 1024 blocks)
    if (ws_ok) {
        gemm_bt<4, 0, 0><<<dim3(EMB / BN, NQ / BM, 4), 256, 0, stream>>>(
            ctxb, Wpb, nullptr, P, nullptr, NQ, EMB, EMB / 4, EMB, EMB);
        reduce_k<4, 1><<<dim3(MN / 1024), 256, 0, stream>>>(
            P, bp, out, nullptr, nullptr, MN, EMB);
    } else {
        gemm_bt<0, 1, 0><<<dim3(EMB / BN, NQ / BM), 256, 0, stream>>>(
            ctxb, Wpb, bp, out, nullptr, NQ, EMB, EMB, EMB, EMB);
    }
}